// Round 1
// baseline (365.423 us; speedup 1.0000x reference)
//
#include <hip/hip_runtime.h>
#include <cstdint>
#include <cstddef>

#define D_MODEL 1024
#define SEQ     2048
#define NHEADS  16
#define HDIM    64

typedef __attribute__((ext_vector_type(8))) __bf16 bf16x8;
typedef __attribute__((ext_vector_type(4))) __bf16 bf16x4;
typedef __attribute__((ext_vector_type(4))) float  f32x4;

// ---------------- elementwise / convert kernels ----------------

__global__ __launch_bounds__(256) void cvt_f32_bf16(const float* __restrict__ in,
                                                    __bf16* __restrict__ out, int n) {
  int i = (blockIdx.x * 256 + threadIdx.x) * 4;
  if (i >= n) return;
  float4 v = *(const float4*)(in + i);
  bf16x4 o;
  o[0] = (__bf16)v.x; o[1] = (__bf16)v.y; o[2] = (__bf16)v.z; o[3] = (__bf16)v.w;
  *(bf16x4*)(out + i) = o;
}

__global__ __launch_bounds__(256) void pack_bias3(const float* __restrict__ b0,
                                                  const float* __restrict__ b1,
                                                  const float* __restrict__ b2,
                                                  float* __restrict__ out) {
  int i = blockIdx.x * 256 + threadIdx.x;  // 0..3071
  float v = (i < 1024) ? b0[i] : (i < 2048) ? b1[i - 1024] : b2[i - 2048];
  out[i] = v;
}

// depthwise conv K=3 pad=1 along sequence; x [B,S,C] f32 -> out [B*S, C] bf16
__global__ __launch_bounds__(256) void dwconv_k(const float* __restrict__ x,
                                                const float* __restrict__ w,   // [C][3]
                                                const float* __restrict__ bias,
                                                __bf16* __restrict__ out) {
  int bs = blockIdx.x;           // b*SEQ + s
  int s  = bs & (SEQ - 1);
  int c  = threadIdx.x * 4;
  const float* xr = x + (size_t)bs * D_MODEL + c;
  float4 x0 = *(const float4*)xr;
  float4 xm = {0.f, 0.f, 0.f, 0.f}, xp = {0.f, 0.f, 0.f, 0.f};
  if (s > 0)       xm = *(const float4*)(xr - D_MODEL);
  if (s < SEQ - 1) xp = *(const float4*)(xr + D_MODEL);
  float4 bb = *(const float4*)(bias + c);
  const float* xmf = (const float*)&xm;
  const float* x0f = (const float*)&x0;
  const float* xpf = (const float*)&xp;
  const float* bbf = (const float*)&bb;
  bf16x4 o;
#pragma unroll
  for (int j = 0; j < 4; ++j) {
    int ch = c + j;
    float a = xmf[j] * w[ch*3 + 0] + x0f[j] * w[ch*3 + 1] + xpf[j] * w[ch*3 + 2] + bbf[j];
    o[j] = (__bf16)a;
  }
  *(bf16x4*)(out + (size_t)bs * D_MODEL + c) = o;
}

// ---------------- GEMM: C[M,N] = A[M,K] @ W[N,K]^T + bias, optional GELU ----
// 128x128 tile, BK=32, 4 waves (each 64x64), mfma_f32_16x16x32_bf16.
// A-frag: row = lane&15, k = 8*(lane>>4)+j ; B-frag: col(n) = lane&15, same k.
// C/D:    col = lane&15, row = 4*(lane>>4)+reg   [verified layout]

template <int EPI, typename OUT_T>   // EPI: 0 = none, 1 = exact GELU
__global__ __launch_bounds__(256) void gemm_bt(
    const __bf16* __restrict__ A, int lda,
    const __bf16* __restrict__ W, int ldw,
    const float* __restrict__ bias,
    OUT_T* __restrict__ C, int ldc, int coff,
    int K)
{
  __shared__ __bf16 sA[128 * 32];
  __shared__ __bf16 sB[128 * 32];
  const int t  = threadIdx.x;
  const int w  = t >> 6, l = t & 63;
  const int bm = blockIdx.x, bn = blockIdx.y;
  const int wr = (w >> 1) * 64, wc = (w & 1) * 64;
  const int tl = l & 15, tg = l >> 4;
  const int srow = t >> 2;            // 0..63
  const int scol = (t & 3) * 8;       // 0,8,16,24

  const f32x4 fzero = {0.f, 0.f, 0.f, 0.f};
  f32x4 acc[4][4];
#pragma unroll
  for (int m = 0; m < 4; ++m)
#pragma unroll
    for (int n = 0; n < 4; ++n) acc[m][n] = fzero;

  const __bf16* Abase = A + (size_t)(bm * 128) * lda;
  const __bf16* Wbase = W + (size_t)(bn * 128) * ldw;

  for (int k0 = 0; k0 < K; k0 += 32) {
#pragma unroll
    for (int p = 0; p < 2; ++p) {
      int r2 = p * 64 + srow;
      *(bf16x8*)&sA[r2 * 32 + scol] = *(const bf16x8*)&Abase[(size_t)r2 * lda + k0 + scol];
      *(bf16x8*)&sB[r2 * 32 + scol] = *(const bf16x8*)&Wbase[(size_t)r2 * ldw + k0 + scol];
    }
    __syncthreads();
    bf16x8 af[4], bfv[4];
#pragma unroll
    for (int m = 0; m < 4; ++m) af[m]  = *(const bf16x8*)&sA[(wr + m*16 + tl) * 32 + tg*8];
#pragma unroll
    for (int n = 0; n < 4; ++n) bfv[n] = *(const bf16x8*)&sB[(wc + n*16 + tl) * 32 + tg*8];
#pragma unroll
    for (int m = 0; m < 4; ++m)
#pragma unroll
      for (int n = 0; n < 4; ++n)
        acc[m][n] = __builtin_amdgcn_mfma_f32_16x16x32_bf16(af[m], bfv[n], acc[m][n], 0, 0, 0);
    __syncthreads();
  }

  const int grow = bm * 128 + wr + tg * 4;
  const int gcolb = bn * 128 + wc + tl;
#pragma unroll
  for (int n = 0; n < 4; ++n) {
    int col = gcolb + n * 16;
    float bv = bias[col];
#pragma unroll
    for (int m = 0; m < 4; ++m) {
#pragma unroll
      for (int r = 0; r < 4; ++r) {
        float v = acc[m][n][r] + bv;
        if (EPI == 1) v = 0.5f * v * (1.0f + erff(v * 0.7071067811865475f));
        C[(size_t)(grow + m * 16 + r) * ldc + coff + col] = (OUT_T)v;
      }
    }
  }
}

// ---------------- flash attention ----------------
// qkv [B*S, 3072] bf16 (q|k|v each 1024 cols, head h at cols h*64..h*64+63)
// one block = 64 q rows of one (b,h); 4 waves x 16 q rows; KV tiles of 64.

__global__ __launch_bounds__(256) void attn_k(const __bf16* __restrict__ QKV,
                                              __bf16* __restrict__ O) {
  const int qb = blockIdx.x, h = blockIdx.y, b = blockIdx.z;
  __shared__ __bf16 sQ[64 * 64];
  __shared__ __bf16 sK[64 * 64];
  __shared__ __bf16 sVt[64 * 64];     // transposed: [d][kv]
  __shared__ __bf16 sP[4 * 16 * 64];  // per-wave P tile [16 q][64 kv]
  const int t = threadIdx.x, w = t >> 6, l = t & 63;
  const int tl = l & 15, g = l >> 4;
  const size_t ldq = 3072;

  const __bf16* Kp = QKV + 1024;
  const __bf16* Vp = QKV + 2048;
  const size_t qoff = ((size_t)(b * SEQ + qb * 64)) * ldq + h * 64;

  for (int i = t; i < 512; i += 256) {
    int r = i >> 3, c = (i & 7) * 8;
    *(bf16x8*)&sQ[r * 64 + c] = *(const bf16x8*)&QKV[qoff + (size_t)r * ldq + c];
  }
  __syncthreads();
  bf16x8 qf0 = *(const bf16x8*)&sQ[(w * 16 + tl) * 64 + g * 8];
  bf16x8 qf1 = *(const bf16x8*)&sQ[(w * 16 + tl) * 64 + 32 + g * 8];

  const f32x4 fzero = {0.f, 0.f, 0.f, 0.f};
  f32x4 acc[4];
#pragma unroll
  for (int nd = 0; nd < 4; ++nd) acc[nd] = fzero;
  float m_run[4], l_run[4];
#pragma unroll
  for (int r = 0; r < 4; ++r) { m_run[r] = -1e30f; l_run[r] = 0.f; }

  for (int kt = 0; kt < SEQ / 64; ++kt) {
    __syncthreads();  // previous iteration's reads done before overwrite
    const size_t kvoff = ((size_t)(b * SEQ + kt * 64)) * ldq + h * 64;
    for (int i = t; i < 512; i += 256) {
      int r = i >> 3, c = (i & 7) * 8;
      *(bf16x8*)&sK[r * 64 + c] = *(const bf16x8*)&Kp[kvoff + (size_t)r * ldq + c];
      bf16x8 vv = *(const bf16x8*)&Vp[kvoff + (size_t)r * ldq + c];
#pragma unroll
      for (int j = 0; j < 8; ++j) sVt[(c + j) * 64 + r] = vv[j];
    }
    __syncthreads();

    // S = Q K^T * (1/8): 16 q rows x 64 kv per wave
    f32x4 sf[4];
#pragma unroll
    for (int n = 0; n < 4; ++n) {
      bf16x8 kf0 = *(const bf16x8*)&sK[(n * 16 + tl) * 64 + g * 8];
      bf16x8 kf1 = *(const bf16x8*)&sK[(n * 16 + tl) * 64 + 32 + g * 8];
      f32x4 z = fzero;
      z = __builtin_amdgcn_mfma_f32_16x16x32_bf16(qf0, kf0, z, 0, 0, 0);
      z = __builtin_amdgcn_mfma_f32_16x16x32_bf16(qf1, kf1, z, 0, 0, 0);
      sf[n] = z;
    }
    float corr[4];
#pragma unroll
    for (int r = 0; r < 4; ++r) {
      float s0 = sf[0][r] * 0.125f, s1 = sf[1][r] * 0.125f;
      float s2 = sf[2][r] * 0.125f, s3 = sf[3][r] * 0.125f;
      float mx = fmaxf(fmaxf(s0, s1), fmaxf(s2, s3));
#pragma unroll
      for (int d = 1; d < 16; d <<= 1) mx = fmaxf(mx, __shfl_xor(mx, d));
      float mn = fmaxf(m_run[r], mx);
      float c0 = __expf(m_run[r] - mn);
      float p0 = __expf(s0 - mn), p1 = __expf(s1 - mn);
      float p2 = __expf(s2 - mn), p3 = __expf(s3 - mn);
      sf[0][r] = p0; sf[1][r] = p1; sf[2][r] = p2; sf[3][r] = p3;
      float ts = p0 + p1 + p2 + p3;
#pragma unroll
      for (int d = 1; d < 16; d <<= 1) ts += __shfl_xor(ts, d);
      l_run[r] = l_run[r] * c0 + ts;
      m_run[r] = mn;
      corr[r] = c0;
    }
    // P -> LDS (layout fix: S-frag rows are 4g+r, PV A-frag wants row=lane&15)
#pragma unroll
    for (int n = 0; n < 4; ++n)
#pragma unroll
      for (int r = 0; r < 4; ++r)
        sP[w * 1024 + (g * 4 + r) * 64 + n * 16 + tl] = (__bf16)sf[n][r];
    __syncthreads();
    // rescale existing accumulator
#pragma unroll
    for (int nd = 0; nd < 4; ++nd)
#pragma unroll
      for (int r = 0; r < 4; ++r) acc[nd][r] *= corr[r];
    // PV
    bf16x8 pf0 = *(const bf16x8*)&sP[w * 1024 + tl * 64 + g * 8];
    bf16x8 pf1 = *(const bf16x8*)&sP[w * 1024 + tl * 64 + 32 + g * 8];
#pragma unroll
    for (int nd = 0; nd < 4; ++nd) {
      bf16x8 vf0 = *(const bf16x8*)&sVt[(nd * 16 + tl) * 64 + g * 8];
      bf16x8 vf1 = *(const bf16x8*)&sVt[(nd * 16 + tl) * 64 + 32 + g * 8];
      acc[nd] = __builtin_amdgcn_mfma_f32_16x16x32_bf16(pf0, vf0, acc[nd], 0, 0, 0);
      acc[nd] = __builtin_amdgcn_mfma_f32_16x16x32_bf16(pf1, vf1, acc[nd], 0, 0, 0);
    }
  }

  const size_t orow = (size_t)(b * SEQ + qb * 64 + w * 16 + g * 4);
#pragma unroll
  for (int r = 0; r < 4; ++r) {
    float inv = 1.0f / l_run[r];
#pragma unroll
    for (int nd = 0; nd < 4; ++nd)
      O[(orow + r) * 1024 + h * 64 + nd * 16 + tl] = (__bf16)(acc[nd][r] * inv);
  }
}

// ---------------- host ----------------

extern "C" void kernel_launch(void* const* d_in, const int* in_sizes, int n_in,
                              void* d_out, int out_size, void* d_ws, size_t ws_size,
                              hipStream_t stream) {
  (void)in_sizes; (void)n_in; (void)out_size; (void)ws_size;
  const float* x   = (const float*)d_in[0];
  const float* wq  = (const float*)d_in[1];
  const float* bq  = (const float*)d_in[2];
  const float* wk  = (const float*)d_in[3];
  const float* bk  = (const float*)d_in[4];
  const float* wv  = (const float*)d_in[5];
  const float* bv  = (const float*)d_in[6];
  const float* wo  = (const float*)d_in[7];
  const float* bo  = (const float*)d_in[8];
  const float* dww = (const float*)d_in[9];
  const float* dwb = (const float*)d_in[10];
  const float* pww = (const float*)d_in[11];
  const float* pwb = (const float*)d_in[12];
  const float* fuw = (const float*)d_in[13];
  const float* fub = (const float*)d_in[14];
  float* out = (float*)d_out;
  char* ws = (char*)d_ws;

  const size_t MB = 1ull << 20;
  __bf16* x_bf  = (__bf16*)(ws + 0);        // 8 MB  [4096][1024]
  __bf16* wqkv  = (__bf16*)(ws + 8  * MB);  // 6 MB  [3072][1024]
  __bf16* wo_bf = (__bf16*)(ws + 14 * MB);  // 2 MB
  __bf16* pw_bf = (__bf16*)(ws + 16 * MB);  // 2 MB
  __bf16* fu_bf = (__bf16*)(ws + 18 * MB);  // 4 MB  [1024][2048]
  float*  bqkv  = (float*) (ws + 22 * MB);  // 12 KB
  __bf16* xdw   = (__bf16*)(ws + 23 * MB);  // 8 MB  [4096][1024]
  __bf16* qkv   = (__bf16*)(ws + 31 * MB);  // 24 MB [4096][3072]
  __bf16* attn  = x_bf;                     // reuse: x_bf dead after QKV GEMM
  __bf16* fused = qkv;                      // reuse: qkv dead after attention (16 MB [4096][2048])

  // conversions
  cvt_f32_bf16<<<4096, 256, 0, stream>>>(x, x_bf, 4194304);
  cvt_f32_bf16<<<1024, 256, 0, stream>>>(wq, wqkv,            1048576);
  cvt_f32_bf16<<<1024, 256, 0, stream>>>(wk, wqkv + 1048576,  1048576);
  cvt_f32_bf16<<<1024, 256, 0, stream>>>(wv, wqkv + 2097152,  1048576);
  cvt_f32_bf16<<<1024, 256, 0, stream>>>(wo, wo_bf, 1048576);
  cvt_f32_bf16<<<1024, 256, 0, stream>>>(pww, pw_bf, 1048576);
  cvt_f32_bf16<<<2048, 256, 0, stream>>>(fuw, fu_bf, 2097152);
  pack_bias3<<<12, 256, 0, stream>>>(bq, bk, bv, bqkv);

  // conv branch: depthwise
  dwconv_k<<<4096, 256, 0, stream>>>(x, dww, dwb, xdw);

  // QKV projection: [4096,1024] @ [3072,1024]^T -> [4096,3072]
  gemm_bt<0, __bf16><<<dim3(32, 24), 256, 0, stream>>>(
      x_bf, 1024, wqkv, 1024, bqkv, qkv, 3072, 0, 1024);

  // attention -> attn [4096,1024]
  attn_k<<<dim3(32, 16, 2), 256, 0, stream>>>(qkv, attn);

  // out-proj -> fused[:, 0:1024]
  gemm_bt<0, __bf16><<<dim3(32, 8), 256, 0, stream>>>(
      attn, 1024, wo_bf, 1024, bo, fused, 2048, 0, 1024);

  // pointwise conv + GELU -> fused[:, 1024:2048]
  gemm_bt<1, __bf16><<<dim3(32, 8), 256, 0, stream>>>(
      xdw, 1024, pw_bf, 1024, pwb, fused, 2048, 1024, 1024);

  // fusion: [4096,2048] @ [1024,2048]^T -> out fp32
  gemm_bt<0, float><<<dim3(32, 8), 256, 0, stream>>>(
      fused, 2048, fu_bf, 2048, fub, out, 1024, 0, 2048);
}

// Round 2
// 298.627 us; speedup vs baseline: 1.2237x; 1.2237x over previous
//
#include <hip/hip_runtime.h>
#include <cstdint>
#include <cstddef>

#define D_MODEL 1024
#define SEQ     2048
#define NHEADS  16
#define HDIM    64

typedef __attribute__((ext_vector_type(8))) __bf16 bf16x8;
typedef __attribute__((ext_vector_type(4))) __bf16 bf16x4;
typedef __attribute__((ext_vector_type(4))) float  f32x4;

// async global->LDS, 16B per lane. LDS dest = wave-uniform base + lane*16.
__device__ __forceinline__ void async16(void* lds, const void* g) {
  __builtin_amdgcn_global_load_lds((const __attribute__((address_space(1))) unsigned int*)g,
                                   (__attribute__((address_space(3))) unsigned int*)lds,
                                   16, 0, 0);
}

// XOR swizzle: flip 16B-slot bits of elem col by (row&7). Rows are 64 bf16 = 128B.
#define SWZ(r, c) ((c) ^ (((r) & 7) << 3))

// ---------------- elementwise / convert kernels ----------------

__global__ __launch_bounds__(256) void cvt_f32_bf16(const float* __restrict__ in,
                                                    __bf16* __restrict__ out, int n) {
  int i = (blockIdx.x * 256 + threadIdx.x) * 4;
  if (i >= n) return;
  float4 v = *(const float4*)(in + i);
  bf16x4 o;
  o[0] = (__bf16)v.x; o[1] = (__bf16)v.y; o[2] = (__bf16)v.z; o[3] = (__bf16)v.w;
  *(bf16x4*)(out + i) = o;
}

__global__ __launch_bounds__(256) void pack_bias3(const float* __restrict__ b0,
                                                  const float* __restrict__ b1,
                                                  const float* __restrict__ b2,
                                                  float* __restrict__ out) {
  int i = blockIdx.x * 256 + threadIdx.x;  // 0..3071
  float v = (i < 1024) ? b0[i] : (i < 2048) ? b1[i - 1024] : b2[i - 2048];
  out[i] = v;
}

// depthwise conv K=3 pad=1 along sequence + center-row bf16 cast (fused).
__global__ __launch_bounds__(256) void dw_cvt_k(const float* __restrict__ x,
                                                const float* __restrict__ w,   // [C][3]
                                                const float* __restrict__ bias,
                                                __bf16* __restrict__ out_dw,
                                                __bf16* __restrict__ out_x) {
  int bs = blockIdx.x;           // b*SEQ + s
  int s  = bs & (SEQ - 1);
  int c  = threadIdx.x * 4;
  const float* xr = x + (size_t)bs * D_MODEL + c;
  float4 x0 = *(const float4*)xr;
  float4 xm = {0.f, 0.f, 0.f, 0.f}, xp = {0.f, 0.f, 0.f, 0.f};
  if (s > 0)       xm = *(const float4*)(xr - D_MODEL);
  if (s < SEQ - 1) xp = *(const float4*)(xr + D_MODEL);
  float4 bb = *(const float4*)(bias + c);
  const float* xmf = (const float*)&xm;
  const float* x0f = (const float*)&x0;
  const float* xpf = (const float*)&xp;
  const float* bbf = (const float*)&bb;
  bf16x4 o, ox;
#pragma unroll
  for (int j = 0; j < 4; ++j) {
    int ch = c + j;
    float a = xmf[j] * w[ch*3 + 0] + x0f[j] * w[ch*3 + 1] + xpf[j] * w[ch*3 + 2] + bbf[j];
    o[j]  = (__bf16)a;
    ox[j] = (__bf16)x0f[j];
  }
  *(bf16x4*)(out_dw + (size_t)bs * D_MODEL + c) = o;
  *(bf16x4*)(out_x  + (size_t)bs * D_MODEL + c) = ox;
}

// ---------------- GEMM: C[M,N] = A[M,K] @ W[N,K]^T + bias, optional GELU ----
// 128x128 tile, BK=32, 4 waves, mfma_f32_16x16x32_bf16, global_load_lds staging.

template <int EPI, typename OUT_T>   // EPI: 0 = none, 1 = exact GELU
__global__ __launch_bounds__(256) void gemm_bt(
    const __bf16* __restrict__ A, int lda,
    const __bf16* __restrict__ W, int ldw,
    const float* __restrict__ bias,
    OUT_T* __restrict__ C, int ldc, int coff,
    int K)
{
  __shared__ __bf16 sA[128 * 32];
  __shared__ __bf16 sB[128 * 32];
  const int t  = threadIdx.x;
  const int w  = t >> 6, l = t & 63;
  const int bm = blockIdx.x, bn = blockIdx.y;
  const int wr = (w >> 1) * 64, wc = (w & 1) * 64;
  const int tl = l & 15, tg = l >> 4;

  const f32x4 fzero = {0.f, 0.f, 0.f, 0.f};
  f32x4 acc[4][4];
#pragma unroll
  for (int m = 0; m < 4; ++m)
#pragma unroll
    for (int n = 0; n < 4; ++n) acc[m][n] = fzero;

  const __bf16* Abase = A + (size_t)(bm * 128) * lda;
  const __bf16* Wbase = W + (size_t)(bn * 128) * ldw;

  // staging geometry: chunk = 1024B = 16 rows of 32 bf16; lane covers 16B
  const int srow = l >> 2;        // 0..15 row within chunk
  const int scol = (l & 3) * 8;   // elem col

  for (int k0 = 0; k0 < K; k0 += 32) {
#pragma unroll
    for (int p = 0; p < 2; ++p) {
      int chunk = w * 2 + p;                 // 0..7
      int r = chunk * 16 + srow;
      async16(&sA[chunk * 512], &Abase[(size_t)r * lda + k0 + scol]);
      async16(&sB[chunk * 512], &Wbase[(size_t)r * ldw + k0 + scol]);
    }
    __syncthreads();
    bf16x8 af[4], bfv[4];
#pragma unroll
    for (int m = 0; m < 4; ++m) af[m]  = *(const bf16x8*)&sA[(wr + m*16 + tl) * 32 + tg*8];
#pragma unroll
    for (int n = 0; n < 4; ++n) bfv[n] = *(const bf16x8*)&sB[(wc + n*16 + tl) * 32 + tg*8];
#pragma unroll
    for (int m = 0; m < 4; ++m)
#pragma unroll
      for (int n = 0; n < 4; ++n)
        acc[m][n] = __builtin_amdgcn_mfma_f32_16x16x32_bf16(af[m], bfv[n], acc[m][n], 0, 0, 0);
    __syncthreads();
  }

  const int grow = bm * 128 + wr + tg * 4;
  const int gcolb = bn * 128 + wc + tl;
#pragma unroll
  for (int n = 0; n < 4; ++n) {
    int col = gcolb + n * 16;
    float bv = bias[col];
#pragma unroll
    for (int m = 0; m < 4; ++m) {
#pragma unroll
      for (int r = 0; r < 4; ++r) {
        float v = acc[m][n][r] + bv;
        if (EPI == 1) v = 0.5f * v * (1.0f + erff(v * 0.7071067811865475f));
        C[(size_t)(grow + m * 16 + r) * ldc + coff + col] = (OUT_T)v;
      }
    }
  }
}

// ---------------- flash attention ----------------
// qkv [B*S, 3072] bf16 (q|k|v each 1024 cols, head h at cols h*64..h*64+63)
// one block = 64 q rows of one (b,h); 4 waves x 16 q rows; KV tiles of 64.
// All LDS tiles XOR-swizzled; K/Q staged via global_load_lds with pre-swizzled
// source; V read transposed straight from global (coalesced b16 per lane).

__global__ __launch_bounds__(256) void attn_k(const __bf16* __restrict__ QKV,
                                              __bf16* __restrict__ O) {
  const int qb = blockIdx.x, h = blockIdx.y, b = blockIdx.z;
  __shared__ __bf16 sQ[64 * 64];
  __shared__ __bf16 sK[64 * 64];
  __shared__ __bf16 sVt[64 * 64];     // transposed: [d][kv], swizzled
  __shared__ __bf16 sP[4 * 16 * 64];  // per-wave P tile [16 q][64 kv], swizzled
  const int t = threadIdx.x, w = t >> 6, l = t & 63;
  const int tl = l & 15, g = l >> 4;
  const int ldq = 3072;

  const __bf16* Kp = QKV + 1024;
  const __bf16* Vp = QKV + 2048;
  const size_t qoff = ((size_t)(b * SEQ + qb * 64)) * ldq + h * 64;

  // staging geometry for 64x64 tile: chunk = 1024B = 8 rows; lane covers 16B
  const int qrow = l >> 3;          // row within chunk
  const int qcol = (l & 7) * 8;     // swizzled col (LDS position)

  // ---- stage Q (pre-swizzled source) ----
#pragma unroll
  for (int p = 0; p < 2; ++p) {
    int chunk = w * 2 + p;
    int r = chunk * 8 + qrow;
    int cg = qcol ^ ((r & 7) << 3);  // inverse swizzle on source col
    async16(&sQ[chunk * 512], &QKV[qoff + (size_t)r * ldq + cg]);
  }
  __syncthreads();
  const int qr = w * 16 + tl;
  bf16x8 qf0 = *(const bf16x8*)&sQ[qr * 64 + SWZ(qr, g * 8)];
  bf16x8 qf1 = *(const bf16x8*)&sQ[qr * 64 + SWZ(qr, 32 + g * 8)];

  const f32x4 fzero = {0.f, 0.f, 0.f, 0.f};
  f32x4 acc[4];
#pragma unroll
  for (int nd = 0; nd < 4; ++nd) acc[nd] = fzero;
  float m_run[4], l_run[4];
#pragma unroll
  for (int r = 0; r < 4; ++r) { m_run[r] = -1e30f; l_run[r] = 0.f; }

  const float SCL = 0.125f * 1.4426950408889634f;  // fold 1/sqrt(d) and log2(e)

  for (int kt = 0; kt < SEQ / 64; ++kt) {
    __syncthreads();  // previous iteration's LDS reads done before overwrite
    const size_t kvoff = ((size_t)(b * SEQ + kt * 64)) * ldq + h * 64;
    // K tile via global_load_lds, pre-swizzled source
#pragma unroll
    for (int p = 0; p < 2; ++p) {
      int chunk = w * 2 + p;
      int r = chunk * 8 + qrow;
      int cg = qcol ^ ((r & 7) << 3);
      async16(&sK[chunk * 512], &Kp[kvoff + (size_t)r * ldq + cg]);
    }
    // V^T: per-lane transposed global read (coalesced along d), swizzled b128 write
#pragma unroll
    for (int pp = 0; pp < 2; ++pp) {
      int d  = l;                    // 0..63
      int k8 = w + pp * 4;           // 0..7
      const __bf16* vsrc = Vp + kvoff + (size_t)(k8 * 8) * ldq + d;
      bf16x8 vv;
#pragma unroll
      for (int j = 0; j < 8; ++j) vv[j] = vsrc[(size_t)j * ldq];
      *(bf16x8*)&sVt[d * 64 + SWZ(d, k8 * 8)] = vv;
    }
    __syncthreads();

    // S = Q K^T (scaled into log2 domain): 16 q rows x 64 kv per wave
    f32x4 sf[4];
#pragma unroll
    for (int n = 0; n < 4; ++n) {
      int kr = n * 16 + tl;
      bf16x8 kf0 = *(const bf16x8*)&sK[kr * 64 + SWZ(kr, g * 8)];
      bf16x8 kf1 = *(const bf16x8*)&sK[kr * 64 + SWZ(kr, 32 + g * 8)];
      f32x4 z = fzero;
      z = __builtin_amdgcn_mfma_f32_16x16x32_bf16(qf0, kf0, z, 0, 0, 0);
      z = __builtin_amdgcn_mfma_f32_16x16x32_bf16(qf1, kf1, z, 0, 0, 0);
      sf[n] = z;
    }
    float corr[4];
#pragma unroll
    for (int r = 0; r < 4; ++r) {
      float s0 = sf[0][r] * SCL, s1 = sf[1][r] * SCL;
      float s2 = sf[2][r] * SCL, s3 = sf[3][r] * SCL;
      float mx = fmaxf(fmaxf(s0, s1), fmaxf(s2, s3));
#pragma unroll
      for (int d = 1; d < 16; d <<= 1) mx = fmaxf(mx, __shfl_xor(mx, d));
      float mn = fmaxf(m_run[r], mx);
      float c0 = exp2f(m_run[r] - mn);
      float p0 = exp2f(s0 - mn), p1 = exp2f(s1 - mn);
      float p2 = exp2f(s2 - mn), p3 = exp2f(s3 - mn);
      sf[0][r] = p0; sf[1][r] = p1; sf[2][r] = p2; sf[3][r] = p3;
      float ts = p0 + p1 + p2 + p3;
#pragma unroll
      for (int d = 1; d < 16; d <<= 1) ts += __shfl_xor(ts, d);
      l_run[r] = l_run[r] * c0 + ts;
      m_run[r] = mn;
      corr[r] = c0;
    }
    // P -> per-wave LDS region (swizzled); no barrier needed (wave-private)
#pragma unroll
    for (int n = 0; n < 4; ++n)
#pragma unroll
      for (int r = 0; r < 4; ++r) {
        int pr = g * 4 + r;
        sP[w * 1024 + pr * 64 + SWZ(pr, n * 16 + tl)] = (__bf16)sf[n][r];
      }
    // rescale existing accumulator
#pragma unroll
    for (int nd = 0; nd < 4; ++nd)
#pragma unroll
      for (int r = 0; r < 4; ++r) acc[nd][r] *= corr[r];
    // PV
    bf16x8 pf0 = *(const bf16x8*)&sP[w * 1024 + tl * 64 + SWZ(tl, g * 8)];
    bf16x8 pf1 = *(const bf16x8*)&sP[w * 1024 + tl * 64 + SWZ(tl, 32 + g * 8)];
#pragma unroll
    for (int nd = 0; nd < 4; ++nd) {
      int vr = nd * 16 + tl;
      bf16x8 vf0 = *(const bf16x8*)&sVt[vr * 64 + SWZ(vr, g * 8)];
      bf16x8 vf1 = *(const bf16x8*)&sVt[vr * 64 + SWZ(vr, 32 + g * 8)];
      acc[nd] = __builtin_amdgcn_mfma_f32_16x16x32_bf16(pf0, vf0, acc[nd], 0, 0, 0);
      acc[nd] = __builtin_amdgcn_mfma_f32_16x16x32_bf16(pf1, vf1, acc[nd], 0, 0, 0);
    }
  }

  const size_t orow = (size_t)(b * SEQ + qb * 64 + w * 16 + g * 4);
#pragma unroll
  for (int r = 0; r < 4; ++r) {
    float inv = 1.0f / l_run[r];
#pragma unroll
    for (int nd = 0; nd < 4; ++nd)
      O[(orow + r) * 1024 + h * 64 + nd * 16 + tl] = (__bf16)(acc[nd][r] * inv);
  }
}

// ---------------- host ----------------

extern "C" void kernel_launch(void* const* d_in, const int* in_sizes, int n_in,
                              void* d_out, int out_size, void* d_ws, size_t ws_size,
                              hipStream_t stream) {
  (void)in_sizes; (void)n_in; (void)out_size; (void)ws_size;
  const float* x   = (const float*)d_in[0];
  const float* wq  = (const float*)d_in[1];
  const float* bq  = (const float*)d_in[2];
  const float* wk  = (const float*)d_in[3];
  const float* bk  = (const float*)d_in[4];
  const float* wv  = (const float*)d_in[5];
  const float* bv  = (const float*)d_in[6];
  const float* wo  = (const float*)d_in[7];
  const float* bo  = (const float*)d_in[8];
  const float* dww = (const float*)d_in[9];
  const float* dwb = (const float*)d_in[10];
  const float* pww = (const float*)d_in[11];
  const float* pwb = (const float*)d_in[12];
  const float* fuw = (const float*)d_in[13];
  const float* fub = (const float*)d_in[14];
  float* out = (float*)d_out;
  char* ws = (char*)d_ws;

  const size_t MB = 1ull << 20;
  __bf16* x_bf  = (__bf16*)(ws + 0);        // 8 MB  [4096][1024]
  __bf16* wqkv  = (__bf16*)(ws + 8  * MB);  // 6 MB  [3072][1024]
  __bf16* wo_bf = (__bf16*)(ws + 14 * MB);  // 2 MB
  __bf16* pw_bf = (__bf16*)(ws + 16 * MB);  // 2 MB
  __bf16* fu_bf = (__bf16*)(ws + 18 * MB);  // 4 MB  [1024][2048]
  float*  bqkv  = (float*) (ws + 22 * MB);  // 12 KB
  __bf16* xdw   = (__bf16*)(ws + 23 * MB);  // 8 MB  [4096][1024]
  __bf16* qkv   = (__bf16*)(ws + 31 * MB);  // 24 MB [4096][3072]
  __bf16* attn  = x_bf;                     // reuse: x_bf dead after QKV GEMM
  __bf16* fused = qkv;                      // reuse: qkv dead after attention

  // conversions
  cvt_f32_bf16<<<1024, 256, 0, stream>>>(wq, wqkv,            1048576);
  cvt_f32_bf16<<<1024, 256, 0, stream>>>(wk, wqkv + 1048576,  1048576);
  cvt_f32_bf16<<<1024, 256, 0, stream>>>(wv, wqkv + 2097152,  1048576);
  cvt_f32_bf16<<<1024, 256, 0, stream>>>(wo, wo_bf, 1048576);
  cvt_f32_bf16<<<1024, 256, 0, stream>>>(pww, pw_bf, 1048576);
  cvt_f32_bf16<<<2048, 256, 0, stream>>>(fuw, fu_bf, 2097152);
  pack_bias3<<<12, 256, 0, stream>>>(bq, bk, bv, bqkv);

  // conv branch: depthwise + x cast (fused)
  dw_cvt_k<<<4096, 256, 0, stream>>>(x, dww, dwb, xdw, x_bf);

  // QKV projection: [4096,1024] @ [3072,1024]^T -> [4096,3072]
  gemm_bt<0, __bf16><<<dim3(32, 24), 256, 0, stream>>>(
      x_bf, 1024, wqkv, 1024, bqkv, qkv, 3072, 0, 1024);

  // attention -> attn [4096,1024]
  attn_k<<<dim3(32, 16, 2), 256, 0, stream>>>(qkv, attn);

  // out-proj -> fused[:, 0:1024]
  gemm_bt<0, __bf16><<<dim3(32, 8), 256, 0, stream>>>(
      attn, 1024, wo_bf, 1024, bo, fused, 2048, 0, 1024);

  // pointwise conv + GELU -> fused[:, 1024:2048]
  gemm_bt<1, __bf16><<<dim3(32, 8), 256, 0, stream>>>(
      xdw, 1024, pw_bf, 1024, pwb, fused, 2048, 1024, 1024);

  // fusion: [4096,2048] @ [1024,2048]^T -> out fp32
  gemm_bt<0, float><<<dim3(32, 8), 256, 0, stream>>>(
      fused, 2048, fu_bf, 2048, fub, out, 1024, 0, 2048);
}

// Round 3
// 240.529 us; speedup vs baseline: 1.5192x; 1.2415x over previous
//
#include <hip/hip_runtime.h>
#include <cstdint>
#include <cstddef>

#define D_MODEL 1024
#define SEQ     2048
#define NHEADS  16
#define HDIM    64

typedef __attribute__((ext_vector_type(8)))  __bf16 bf16x8;
typedef __attribute__((ext_vector_type(4)))  __bf16 bf16x4;
typedef __attribute__((ext_vector_type(4)))  float  f32x4;
typedef __attribute__((ext_vector_type(16))) float  f32x16;
typedef __attribute__((ext_vector_type(4)))  unsigned u32x4;

// Q pre-scale: 1/sqrt(64) * log2(e)  (QK^T lands directly in log2 domain)
#define QSCALE 0.18033688011112042f

// async global->LDS, 16B per lane. LDS dest = wave-uniform base + lane*16.
__device__ __forceinline__ void async16(void* lds, const void* g) {
  __builtin_amdgcn_global_load_lds((const __attribute__((address_space(1))) unsigned int*)g,
                                   (__attribute__((address_space(3))) unsigned int*)lds,
                                   16, 0, 0);
}

// XOR swizzle: flip 16B-slot bits of elem col by (row&7). Rows are 64 bf16 = 128B.
#define SWZ(r, c) ((c) ^ (((r) & 7) << 3))

__device__ __forceinline__ unsigned cvtpk(float lo, float hi) {
  unsigned r;
  asm("v_cvt_pk_bf16_f32 %0, %1, %2" : "=v"(r) : "v"(lo), "v"(hi));
  return r;
}

// ---------------- elementwise / convert kernels ----------------

__global__ __launch_bounds__(256) void cvt_f32_bf16(const float* __restrict__ in,
                                                    __bf16* __restrict__ out, int n) {
  int i = (blockIdx.x * 256 + threadIdx.x) * 4;
  if (i >= n) return;
  float4 v = *(const float4*)(in + i);
  bf16x4 o;
  o[0] = (__bf16)v.x; o[1] = (__bf16)v.y; o[2] = (__bf16)v.z; o[3] = (__bf16)v.w;
  *(bf16x4*)(out + i) = o;
}

__global__ __launch_bounds__(256) void pack_bias3(const float* __restrict__ b0,
                                                  const float* __restrict__ b1,
                                                  const float* __restrict__ b2,
                                                  float* __restrict__ out) {
  int i = blockIdx.x * 256 + threadIdx.x;  // 0..3071
  float v = (i < 1024) ? b0[i] : (i < 2048) ? b1[i - 1024] : b2[i - 2048];
  out[i] = v;
}

// depthwise conv K=3 pad=1 along sequence + center-row bf16 cast (fused).
__global__ __launch_bounds__(256) void dw_cvt_k(const float* __restrict__ x,
                                                const float* __restrict__ w,   // [C][3]
                                                const float* __restrict__ bias,
                                                __bf16* __restrict__ out_dw,
                                                __bf16* __restrict__ out_x) {
  int bs = blockIdx.x;           // b*SEQ + s
  int s  = bs & (SEQ - 1);
  int c  = threadIdx.x * 4;
  const float* xr = x + (size_t)bs * D_MODEL + c;
  float4 x0 = *(const float4*)xr;
  float4 xm = {0.f, 0.f, 0.f, 0.f}, xp = {0.f, 0.f, 0.f, 0.f};
  if (s > 0)       xm = *(const float4*)(xr - D_MODEL);
  if (s < SEQ - 1) xp = *(const float4*)(xr + D_MODEL);
  float4 bb = *(const float4*)(bias + c);
  const float* xmf = (const float*)&xm;
  const float* x0f = (const float*)&x0;
  const float* xpf = (const float*)&xp;
  const float* bbf = (const float*)&bb;
  bf16x4 o, ox;
#pragma unroll
  for (int j = 0; j < 4; ++j) {
    int ch = c + j;
    float a = xmf[j] * w[ch*3 + 0] + x0f[j] * w[ch*3 + 1] + xpf[j] * w[ch*3 + 2] + bbf[j];
    o[j]  = (__bf16)a;
    ox[j] = (__bf16)x0f[j];
  }
  *(bf16x4*)(out_dw + (size_t)bs * D_MODEL + c) = o;
  *(bf16x4*)(out_x  + (size_t)bs * D_MODEL + c) = ox;
}

// ---------------- GEMM core: C[M,N] = A[M,K] @ W[N,K]^T + bias --------------
// 128x128 tile, BK=32, 4 waves, mfma_f32_16x16x32_bf16, global_load_lds staging.
// epi: 0 none, 1 exact GELU, 2 scale cols<1024 by QSCALE.

template <typename OUT_T>
__device__ __forceinline__ void gemm_core(
    const __bf16* A, int lda, const __bf16* W, int ldw,
    const float* bias, OUT_T* C, int ldc, int coff, int K, int epi,
    __bf16* sA, __bf16* sB, int bm, int bn)
{
  const int t  = threadIdx.x;
  const int w  = t >> 6, l = t & 63;
  const int wr = (w >> 1) * 64, wc = (w & 1) * 64;
  const int tl = l & 15, tg = l >> 4;

  const f32x4 fzero = {0.f, 0.f, 0.f, 0.f};
  f32x4 acc[4][4];
#pragma unroll
  for (int m = 0; m < 4; ++m)
#pragma unroll
    for (int n = 0; n < 4; ++n) acc[m][n] = fzero;

  const __bf16* Abase = A + (size_t)(bm * 128) * lda;
  const __bf16* Wbase = W + (size_t)(bn * 128) * ldw;

  const int srow = l >> 2;        // 0..15 row within chunk
  const int scol = (l & 3) * 8;   // elem col

  for (int k0 = 0; k0 < K; k0 += 32) {
#pragma unroll
    for (int p = 0; p < 2; ++p) {
      int chunk = w * 2 + p;                 // 0..7
      int r = chunk * 16 + srow;
      async16(&sA[chunk * 512], &Abase[(size_t)r * lda + k0 + scol]);
      async16(&sB[chunk * 512], &Wbase[(size_t)r * ldw + k0 + scol]);
    }
    __syncthreads();
    bf16x8 af[4], bfv[4];
#pragma unroll
    for (int m = 0; m < 4; ++m) af[m]  = *(const bf16x8*)&sA[(wr + m*16 + tl) * 32 + tg*8];
#pragma unroll
    for (int n = 0; n < 4; ++n) bfv[n] = *(const bf16x8*)&sB[(wc + n*16 + tl) * 32 + tg*8];
#pragma unroll
    for (int m = 0; m < 4; ++m)
#pragma unroll
      for (int n = 0; n < 4; ++n)
        acc[m][n] = __builtin_amdgcn_mfma_f32_16x16x32_bf16(af[m], bfv[n], acc[m][n], 0, 0, 0);
    __syncthreads();
  }

  const int grow = bm * 128 + wr + tg * 4;
  const int gcolb = bn * 128 + wc + tl;
#pragma unroll
  for (int n = 0; n < 4; ++n) {
    int col = gcolb + n * 16;
    float bv = bias[col];
#pragma unroll
    for (int m = 0; m < 4; ++m) {
#pragma unroll
      for (int r = 0; r < 4; ++r) {
        float v = acc[m][n][r] + bv;
        if (epi == 1) v = 0.5f * v * (1.0f + erff(v * 0.7071067811865475f));
        if (epi == 2 && col < 1024) v *= QSCALE;
        C[(size_t)(grow + m * 16 + r) * ldc + coff + col] = (OUT_T)v;
      }
    }
  }
}

template <typename OUT_T>
__global__ __launch_bounds__(256) void gemm_bt(
    const __bf16* __restrict__ A, int lda,
    const __bf16* __restrict__ W, int ldw,
    const float* __restrict__ bias,
    OUT_T* __restrict__ C, int ldc, int coff, int K, int epi)
{
  __shared__ __bf16 sA[128 * 32];
  __shared__ __bf16 sB[128 * 32];
  gemm_core<OUT_T>(A, lda, W, ldw, bias, C, ldc, coff, K, epi, sA, sB,
                   blockIdx.x, blockIdx.y);
}

// out-proj (z=0) and pointwise-conv+GELU (z=1) in one dispatch
__global__ __launch_bounds__(256) void gemm_dual(
    const __bf16* A0, const __bf16* W0, const float* b0,
    const __bf16* A1, const __bf16* W1, const float* b1,
    __bf16* C)
{
  __shared__ __bf16 sA[128 * 32];
  __shared__ __bf16 sB[128 * 32];
  const int z = blockIdx.z;
  gemm_core<__bf16>(z ? A1 : A0, 1024, z ? W1 : W0, 1024, z ? b1 : b0,
                    C, 2048, z * 1024, 1024, z ? 1 : 0, sA, sB,
                    blockIdx.x, blockIdx.y);
}

// ---------------- V transpose: qkv V-cols -> vt[b][h][64][SEQ] ----------------
__global__ __launch_bounds__(256) void vtrans_k(const __bf16* __restrict__ QKV,
                                                __bf16* __restrict__ VT) {
  const int stile = blockIdx.x, h = blockIdx.y, b = blockIdx.z;
  __shared__ __bf16 ld[64 * 64];
  const int t = threadIdx.x;
  const size_t vbase = ((size_t)(b * SEQ + stile * 64)) * 3072 + 2048 + h * 64;
  // load 64 s-rows x 64 d-cols, swizzled b128 writes (coalesced global reads)
#pragma unroll
  for (int p = 0; p < 2; ++p) {
    int r = p * 32 + (t >> 3);
    int c = (t & 7) * 8;
    *(bf16x8*)&ld[r * 64 + (c ^ ((r & 7) << 3))] =
        *(const bf16x8*)&QKV[vbase + (size_t)r * 3072 + c];
  }
  __syncthreads();
  const size_t obase = ((size_t)(b * NHEADS + h) * 64) * SEQ + stile * 64;
  // write vt rows (d) coalesced; LDS gather (8-way conflict, negligible here)
#pragma unroll
  for (int p = 0; p < 2; ++p) {
    int d  = p * 32 + (t >> 3);
    int s8 = (t & 7) * 8;
    bf16x8 vv;
#pragma unroll
    for (int j = 0; j < 8; ++j) {
      int s = s8 + j;
      vv[j] = ld[s * 64 + (((d & 56) ^ ((s & 7) << 3)) + (d & 7))];
    }
    *(bf16x8*)&VT[obase + (size_t)d * SEQ + s8] = vv;
  }
}

// ---------------- flash attention, swapped-QK^T 32x32 structure --------------
// qkv [B*S,3072] bf16 (Q cols 0-1023 PRE-SCALED by QSCALE, K 1024-2047).
// vt  [b][h][64][SEQ]. Block = 128 q rows of one (b,h); 4 waves x QBLK=32.
// KV tile 64. Lane owns q = lane&31 for softmax (lane^32 holds other 32 kv).

__global__ __launch_bounds__(256) void attn_k(const __bf16* __restrict__ QKV,
                                              const __bf16* __restrict__ VT,
                                              __bf16* __restrict__ O) {
  const int qblk = blockIdx.x, h = blockIdx.y, b = blockIdx.z;
  __shared__ __bf16 sQ[128 * 64];
  __shared__ __bf16 sK[64 * 64];
  __shared__ __bf16 sVt[64 * 64];
  const int t = threadIdx.x, w = t >> 6, l = t & 63;
  const int l31 = l & 31, hi = l >> 5;
  const int ldq = 3072;
  const int srow  = l >> 3;        // row within 1KB chunk (8 rows)
  const int scol0 = (l & 7) * 8;

  const size_t qbase  = ((size_t)(b * SEQ + qblk * 128)) * ldq + h * 64;
  const size_t kbase0 = ((size_t)(b * SEQ)) * ldq + 1024 + h * 64;
  const size_t vtb    = ((size_t)(b * NHEADS + h) * 64) * SEQ;

  // stage Q tile [128][64] (pre-swizzled source)
#pragma unroll
  for (int p = 0; p < 4; ++p) {
    int c = w * 4 + p;                    // 0..15
    int r = c * 8 + srow;
    int cg = scol0 ^ ((r & 7) << 3);
    async16(&sQ[c * 512], &QKV[qbase + (size_t)r * ldq + cg]);
  }
  __syncthreads();
  bf16x8 qf[4];
  const int qr = w * 32 + l31;
#pragma unroll
  for (int kk = 0; kk < 4; ++kk)
    qf[kk] = *(const bf16x8*)&sQ[qr * 64 + SWZ(qr, kk * 16 + 8 * hi)];

  f32x16 acc0, acc1;
#pragma unroll
  for (int r = 0; r < 16; ++r) { acc0[r] = 0.f; acc1[r] = 0.f; }
  float m_run = -1e30f, l_run = 0.f;

  for (int kt = 0; kt < SEQ / 64; ++kt) {
    __syncthreads();  // prev tile's LDS reads complete
    const size_t kb = kbase0 + (size_t)(kt * 64) * ldq;
    const size_t vb = vtb + kt * 64;
#pragma unroll
    for (int p = 0; p < 2; ++p) {
      int c = w * 2 + p;                  // 0..7
      int r = c * 8 + srow;
      int cg = scol0 ^ ((r & 7) << 3);
      async16(&sK[c * 512],  &QKV[kb + (size_t)r * ldq + cg]);
      async16(&sVt[c * 512], &VT[vb + (size_t)r * SEQ + cg]);
    }
    __syncthreads();

    // ST[kv][q] = K · Q^T  (Q pre-scaled -> log2 domain)
    f32x16 st0, st1;
#pragma unroll
    for (int r = 0; r < 16; ++r) { st0[r] = 0.f; st1[r] = 0.f; }
#pragma unroll
    for (int kk = 0; kk < 4; ++kk) {
      int kc = kk * 16 + 8 * hi;
      bf16x8 kf0 = *(const bf16x8*)&sK[l31 * 64 + SWZ(l31, kc)];
      bf16x8 kf1 = *(const bf16x8*)&sK[(l31 + 32) * 64 + SWZ(l31 + 32, kc)];
      st0 = __builtin_amdgcn_mfma_f32_32x32x16_bf16(kf0, qf[kk], st0, 0, 0, 0);
      st1 = __builtin_amdgcn_mfma_f32_32x32x16_bf16(kf1, qf[kk], st1, 0, 0, 0);
    }

    // in-lane max over 32 kv, then exchange with partner lane (lane^32)
    float a0 = fmaxf(fmaxf(st0[0], st0[1]),  fmaxf(st0[2], st0[3]));
    float a1 = fmaxf(fmaxf(st0[4], st0[5]),  fmaxf(st0[6], st0[7]));
    float a2 = fmaxf(fmaxf(st0[8], st0[9]),  fmaxf(st0[10], st0[11]));
    float a3 = fmaxf(fmaxf(st0[12], st0[13]), fmaxf(st0[14], st0[15]));
    float b0 = fmaxf(fmaxf(st1[0], st1[1]),  fmaxf(st1[2], st1[3]));
    float b1 = fmaxf(fmaxf(st1[4], st1[5]),  fmaxf(st1[6], st1[7]));
    float b2 = fmaxf(fmaxf(st1[8], st1[9]),  fmaxf(st1[10], st1[11]));
    float b3 = fmaxf(fmaxf(st1[12], st1[13]), fmaxf(st1[14], st1[15]));
    float mx = fmaxf(fmaxf(fmaxf(a0, a1), fmaxf(a2, a3)),
                     fmaxf(fmaxf(b0, b1), fmaxf(b2, b3)));
    float pmax = fmaxf(mx, __shfl_xor(mx, 32));

    // defer-max: rescale only when max grew by >8 (log2 units)
    if (!__all(pmax <= m_run + 8.0f)) {
      float mn = fmaxf(m_run, pmax);
      float c0 = exp2f(m_run - mn);
      m_run = mn;
      l_run *= c0;
#pragma unroll
      for (int r = 0; r < 16; ++r) {
        int qrow = (r & 3) + 8 * (r >> 2) + 4 * hi;
        float cc = __shfl(c0, qrow);
        acc0[r] *= cc; acc1[r] *= cc;
      }
    }

    // exp2 + per-lane partial sums
    float ts0 = 0.f, ts1 = 0.f, ts2 = 0.f, ts3 = 0.f;
#pragma unroll
    for (int r = 0; r < 16; r += 4) {
      st0[r]   = exp2f(st0[r]   - m_run); ts0 += st0[r];
      st0[r+1] = exp2f(st0[r+1] - m_run); ts1 += st0[r+1];
      st0[r+2] = exp2f(st0[r+2] - m_run); ts2 += st0[r+2];
      st0[r+3] = exp2f(st0[r+3] - m_run); ts3 += st0[r+3];
    }
#pragma unroll
    for (int r = 0; r < 16; r += 4) {
      st1[r]   = exp2f(st1[r]   - m_run); ts0 += st1[r];
      st1[r+1] = exp2f(st1[r+1] - m_run); ts1 += st1[r+1];
      st1[r+2] = exp2f(st1[r+2] - m_run); ts2 += st1[r+2];
      st1[r+3] = exp2f(st1[r+3] - m_run); ts3 += st1[r+3];
    }
    float ts = (ts0 + ts1) + (ts2 + ts3);
    l_run += ts + __shfl_xor(ts, 32);

    // P -> PV A-fragments fully in-register (cvt_pk + half-exchange)
    bf16x8 pa[4];
#pragma unroll
    for (int ks = 0; ks < 4; ++ks) {
      const int base = (ks & 1) * 8;
      float p0, p1, p2, p3, p4, p5, p6, p7;
      if (ks < 2) {
        p0 = st0[base+0]; p1 = st0[base+1]; p2 = st0[base+2]; p3 = st0[base+3];
        p4 = st0[base+4]; p5 = st0[base+5]; p6 = st0[base+6]; p7 = st0[base+7];
      } else {
        p0 = st1[base+0]; p1 = st1[base+1]; p2 = st1[base+2]; p3 = st1[base+3];
        p4 = st1[base+4]; p5 = st1[base+5]; p6 = st1[base+6]; p7 = st1[base+7];
      }
      unsigned A1 = cvtpk(p0, p1), A2 = cvtpk(p2, p3);
      unsigned B1 = cvtpk(p4, p5), B2 = cvtpk(p6, p7);
      unsigned sA1 = (unsigned)__shfl_xor((int)A1, 32);
      unsigned sA2 = (unsigned)__shfl_xor((int)A2, 32);
      unsigned sB1 = (unsigned)__shfl_xor((int)B1, 32);
      unsigned sB2 = (unsigned)__shfl_xor((int)B2, 32);
      u32x4 pw;
      pw[0] = hi ? sB1 : A1;   // kv base+0,1
      pw[1] = hi ? sB2 : A2;   // kv base+2,3
      pw[2] = hi ? B1 : sA1;   // kv base+4,5
      pw[3] = hi ? B2 : sA2;   // kv base+6,7
      pa[ks] = __builtin_bit_cast(bf16x8, pw);
    }

    // O += P · V  (V^T tiles from LDS)
#pragma unroll
    for (int ks = 0; ks < 4; ++ks) {
      int vc = ks * 16 + 8 * hi;
      bf16x8 vf0 = *(const bf16x8*)&sVt[l31 * 64 + SWZ(l31, vc)];
      bf16x8 vf1 = *(const bf16x8*)&sVt[(l31 + 32) * 64 + SWZ(l31 + 32, vc)];
      acc0 = __builtin_amdgcn_mfma_f32_32x32x16_bf16(pa[ks], vf0, acc0, 0, 0, 0);
      acc1 = __builtin_amdgcn_mfma_f32_32x32x16_bf16(pa[ks], vf1, acc1, 0, 0, 0);
    }
  }

  // epilogue: normalize (l_run lives at lane q; O rows live at reg-index q)
  float invl = 1.0f / l_run;
  const size_t obase = (size_t)(b * SEQ + qblk * 128 + w * 32);
#pragma unroll
  for (int r = 0; r < 16; ++r) {
    int qrow = (r & 3) + 8 * (r >> 2) + 4 * hi;
    float inv = __shfl(invl, qrow);
    size_t row = (obase + qrow) * 1024 + h * 64;
    O[row + l31]      = (__bf16)(acc0[r] * inv);
    O[row + 32 + l31] = (__bf16)(acc1[r] * inv);
  }
}

// ---------------- host ----------------

extern "C" void kernel_launch(void* const* d_in, const int* in_sizes, int n_in,
                              void* d_out, int out_size, void* d_ws, size_t ws_size,
                              hipStream_t stream) {
  (void)in_sizes; (void)n_in; (void)out_size; (void)ws_size;
  const float* x   = (const float*)d_in[0];
  const float* wq  = (const float*)d_in[1];
  const float* bq  = (const float*)d_in[2];
  const float* wk  = (const float*)d_in[3];
  const float* bk  = (const float*)d_in[4];
  const float* wv  = (const float*)d_in[5];
  const float* bv  = (const float*)d_in[6];
  const float* wo  = (const float*)d_in[7];
  const float* bo  = (const float*)d_in[8];
  const float* dww = (const float*)d_in[9];
  const float* dwb = (const float*)d_in[10];
  const float* pww = (const float*)d_in[11];
  const float* pwb = (const float*)d_in[12];
  const float* fuw = (const float*)d_in[13];
  const float* fub = (const float*)d_in[14];
  float* out = (float*)d_out;
  char* ws = (char*)d_ws;

  const size_t MB = 1ull << 20;
  // lifetime-packed workspace, peak 48 MB:
  __bf16* x_bf     = (__bf16*)(ws + 0);        // 8MB; dead after QKV gemm
  __bf16* vt       = (__bf16*)(ws + 0);        // reuses x_bf (written after)
  __bf16* wqkv     = (__bf16*)(ws + 8  * MB);  // 6MB; dead after QKV gemm
  float*  bqkv     = (float*) (ws + 14 * MB);  // 12KB; dead after QKV gemm
  __bf16* attn_out = (__bf16*)(ws + 8  * MB);  // 8MB [8,16); written by attn
  __bf16* xdw      = (__bf16*)(ws + 16 * MB);  // 8MB [16,24)
  __bf16* qkv      = (__bf16*)(ws + 24 * MB);  // 24MB [24,48); dead after attn
  __bf16* fused    = qkv;                      // 16MB [24,40) after attn
  __bf16* wo_bf    = (__bf16*)(ws + 40 * MB);  // 2MB (qkv tail, after attn)
  __bf16* pw_bf    = (__bf16*)(ws + 42 * MB);  // 2MB
  __bf16* fu_bf    = (__bf16*)(ws + 44 * MB);  // 4MB

  pack_bias3<<<12, 256, 0, stream>>>(bq, bk, bv, bqkv);
  dw_cvt_k<<<4096, 256, 0, stream>>>(x, dww, dwb, xdw, x_bf);
  cvt_f32_bf16<<<1024, 256, 0, stream>>>(wq, wqkv,           1048576);
  cvt_f32_bf16<<<1024, 256, 0, stream>>>(wk, wqkv + 1048576, 1048576);
  cvt_f32_bf16<<<1024, 256, 0, stream>>>(wv, wqkv + 2097152, 1048576);

  // QKV projection (Q cols scaled by QSCALE): [4096,1024]@[3072,1024]^T
  gemm_bt<__bf16><<<dim3(32, 24), 256, 0, stream>>>(
      x_bf, 1024, wqkv, 1024, bqkv, qkv, 3072, 0, 1024, 2);

  // V transpose -> vt[b][h][64][SEQ]
  vtrans_k<<<dim3(32, 16, 2), 256, 0, stream>>>(qkv, vt);

  // attention -> attn_out [4096,1024]
  attn_k<<<dim3(16, 16, 2), 256, 0, stream>>>(qkv, vt, attn_out);

  // weight conversions into dead qkv tail
  cvt_f32_bf16<<<1024, 256, 0, stream>>>(wo,  wo_bf, 1048576);
  cvt_f32_bf16<<<1024, 256, 0, stream>>>(pww, pw_bf, 1048576);
  cvt_f32_bf16<<<2048, 256, 0, stream>>>(fuw, fu_bf, 2097152);

  // out-proj (z=0) + pointwise GELU (z=1) -> fused [4096,2048]
  gemm_dual<<<dim3(32, 8, 2), 256, 0, stream>>>(
      attn_out, wo_bf, bo, xdw, pw_bf, pwb, fused);

  // fusion: [4096,2048] @ [1024,2048]^T -> out fp32
  gemm_bt<float><<<dim3(32, 8), 256, 0, stream>>>(
      fused, 2048, fu_bf, 2048, fub, out, 1024, 0, 2048, 0);
}